// Round 8
// baseline (944.999 us; speedup 1.0000x reference)
//
#include <hip/hip_runtime.h>

// VQ codebook: z_e (262144, 64) f32, embeddings (512, 64) f32.
// Outputs (flat f32 in d_out): z_q_st [N*D], indices-as-float [N], loss [1].
//
// R8: codebook split ACROSS WAVES. 64 tokens/block in a 16.6KB padded LDS
// tile (read once from HBM); 4 waves/block, wave w = code slice [128w,128w+128)
// in 4 sub-panels of acc[32] (~55 VGPR, under the 64-VGPR allocator cap that
// R1-R4/R7 proved unbreakable). Lane = token -> e rows stay wave-uniform
// (SGPR broadcast, the only free operand path). z re-reads hit LDS, not HBM
// (R6 lesson: 850MB beyond-L2 re-reads = the wall). LDS ~18.7KB -> 8 blocks/CU
// -> 8 waves/SIMD (R5 lesson: 2 waves/SIMD cannot hide ds/smem latency).
// Slice argmin combined in ascending-slice order, strict < => jnp first-min.

static constexpr int N_TOK   = 262144;
static constexpr int K       = 512;
static constexpr int D       = 64;
static constexpr int BLK     = 256;          // 4 waves
static constexpr int TPB     = 64;           // tokens per block
static constexpr int NBLK    = N_TOK / TPB;  // 4096
static constexpr int NSLICE  = 4;            // one slice per wave
static constexpr int SLICE   = K / NSLICE;   // 128 codes
static constexpr int PANEL   = 32;
static constexpr int PPS     = SLICE / PANEL;  // 4 sub-panels
static constexpr int ZSTRIDE = D + 1;        // 65 -> ds_read_b32 2-way = free

// ---- prep 0: esq[k] = ||e_k||^2 --------------------------------------------
__global__ void esq_kernel(const float* __restrict__ emb, float* __restrict__ esq) {
  int k = threadIdx.x;
  if (k < K) {
    const float4* row = reinterpret_cast<const float4*>(emb + (size_t)k * D);
    float s = 0.f;
#pragma unroll
    for (int i = 0; i < D / 4; ++i) {
      float4 v = row[i];
      s = fmaf(v.x, v.x, s);
      s = fmaf(v.y, v.y, s);
      s = fmaf(v.z, v.z, s);
      s = fmaf(v.w, v.w, s);
    }
    esq[k] = s;
  }
}

// ---- prep 1: embT[d][c] = emb[c][d] ----------------------------------------
__global__ __launch_bounds__(512) void embT_kernel(
    const float* __restrict__ emb, float* __restrict__ embT) {
  int idx = blockIdx.x * 512 + threadIdx.x;  // 64 blocks x 512
  int d = idx >> 9;
  int c = idx & 511;
  embT[idx] = emb[c * D + d];
}

// ---- main ------------------------------------------------------------------
__global__ __launch_bounds__(BLK) void vq_main(
    const float* __restrict__ z_e, const float* __restrict__ emb,
    const float* __restrict__ embT, const float* __restrict__ esq,
    float* __restrict__ out_zq, float* __restrict__ out_idx,
    float* __restrict__ block_loss) {
  __shared__ float zs[TPB * ZSTRIDE];     // 64*65*4 = 16.64 KiB
  __shared__ float fb[NSLICE][TPB];       // per-slice best distance
  __shared__ int   fi[NSLICE][TPB];       // per-slice best index

  const int t     = threadIdx.x;
  const int tok   = t & 63;               // lane = token
  const int slice = t >> 6;               // wave id = code slice
  const int gtok0 = blockIdx.x * TPB;

  // Stage 64 z rows once (coalesced float4 reads, scalar scatter into pad).
  {
    const float4* Z4 = reinterpret_cast<const float4*>(z_e + (size_t)gtok0 * D);
#pragma unroll
    for (int i = 0; i < (TPB * D / 4) / BLK; ++i) {  // 4 iters
      int i4 = t + i * BLK;               // 0..1023
      float4 v = Z4[i4];
      int tk = i4 >> 4;                   // 16 float4 per token
      int d4 = (i4 & 15) << 2;
      float* p = &zs[tk * ZSTRIDE + d4];
      p[0] = v.x; p[1] = v.y; p[2] = v.z; p[3] = v.w;
    }
  }
  __syncthreads();

  const float* zrow  = &zs[tok * ZSTRIDE];
  const int    cbase = slice * SLICE;

  float best = 3.402823466e38f;
  int   bidx = 0;

  for (int p = 0; p < PPS; ++p) {
    const float* Ep = embT + cbase + p * PANEL;  // +d*K per row; wave-uniform
    const float* es = esq + cbase + p * PANEL;   // wave-uniform
    float acc[PANEL];
#pragma unroll
    for (int c = 0; c < PANEL; ++c) acc[c] = 0.f;

    // d ascending, single acc chain per code == R5/R6/R7 order (absmax 0).
#pragma unroll 8
    for (int d = 0; d < D; ++d) {
      float zd = zrow[d];                 // ds_read_b32, bank (tok+d)%32
      const float* e = Ep + (size_t)d * K;
#pragma unroll
      for (int c = 0; c < PANEL; ++c) acc[c] = fmaf(zd, e[c], acc[c]);
    }

#pragma unroll
    for (int c = 0; c < PANEL; ++c) {
      float s = fmaf(-2.f, acc[c], es[c]);
      // Ascending c within ascending panels + strict < -> first-min ties.
      if (s < best) { best = s; bidx = cbase + p * PANEL + c; }
    }
  }

  fb[slice][tok] = best;
  fi[slice][tok] = bidx;
  __syncthreads();

  // Wave 0: combine 4 slice candidates per token (ascending slice order),
  // then gather + z_q_st write + loss for its lane's token.
  if (slice == 0) {
    float b  = fb[0][tok];
    int   bi = fi[0][tok];
#pragma unroll
    for (int s2 = 1; s2 < NSLICE; ++s2) {
      float v  = fb[s2][tok];
      int   vi = fi[s2][tok];
      if (v < b) { b = v; bi = vi; }  // strict <: lower slice wins ties
    }

    const int n = gtok0 + tok;
    float lsum = 0.f;
    {
      const float4* er = reinterpret_cast<const float4*>(emb + (size_t)bi * D);
      float4* orow = reinterpret_cast<float4*>(out_zq + (size_t)n * D);
#pragma unroll
      for (int i = 0; i < D / 4; ++i) {
        float4 q = er[i];
        float z0 = zrow[4 * i + 0], z1 = zrow[4 * i + 1];
        float z2 = zrow[4 * i + 2], z3 = zrow[4 * i + 3];
        float dx = q.x - z0, dy = q.y - z1, dz = q.z - z2, dw = q.w - z3;
        float4 st;
        st.x = z0 + dx; st.y = z1 + dy; st.z = z2 + dz; st.w = z3 + dw;
        orow[i] = st;
        lsum = fmaf(dx, dx, lsum);
        lsum = fmaf(dy, dy, lsum);
        lsum = fmaf(dz, dz, lsum);
        lsum = fmaf(dw, dw, lsum);
      }
    }
    out_idx[n] = (float)bi;

    // Deterministic 64-lane butterfly sum (same sequence every launch).
    float s = lsum;
#pragma unroll
    for (int off = 32; off > 0; off >>= 1) s += __shfl_xor(s, off, 64);
    if (tok == 0) block_loss[blockIdx.x] = s;
  }
}

// ---- finalize loss (deterministic tree) ------------------------------------
__global__ __launch_bounds__(256) void loss_finalize(
    const float* __restrict__ bl, float* __restrict__ out_loss) {
  __shared__ float sm[256];
  float s = 0.f;
  for (int i = threadIdx.x; i < NBLK; i += 256) s += bl[i];
  sm[threadIdx.x] = s;
  __syncthreads();
#pragma unroll
  for (int off = 128; off > 0; off >>= 1) {
    if (threadIdx.x < off) sm[threadIdx.x] += sm[threadIdx.x + off];
    __syncthreads();
  }
  if (threadIdx.x == 0) out_loss[0] = sm[0] * (1.0f / 16777216.0f);  // /(N*D)
}

extern "C" void kernel_launch(void* const* d_in, const int* in_sizes, int n_in,
                              void* d_out, int out_size, void* d_ws, size_t ws_size,
                              hipStream_t stream) {
  const float* z_e = (const float*)d_in[0];
  const float* emb = (const float*)d_in[1];

  float* out      = (float*)d_out;
  float* out_zq   = out;                          // N*D
  float* out_idx  = out + (size_t)N_TOK * D;      // N
  float* out_loss = out_idx + N_TOK;              // 1

  float* esq  = (float*)d_ws;            // K floats
  float* bl   = esq + K;                 // NBLK floats (4096)
  float* embT = bl + NBLK;               // K*D floats (128 KiB)

  esq_kernel<<<1, K, 0, stream>>>(emb, esq);
  embT_kernel<<<(K * D) / 512, 512, 0, stream>>>(emb, embT);
  vq_main<<<NBLK, BLK, 0, stream>>>(z_e, emb, embT, esq, out_zq, out_idx, bl);
  loss_finalize<<<1, 256, 0, stream>>>(bl, out_loss);
}

// Round 9
// 214.551 us; speedup vs baseline: 4.4045x; 4.4045x over previous
//
#include <hip/hip_runtime.h>

// VQ codebook: z_e (262144, 64) f32, embeddings (512, 64) f32.
// Outputs (flat f32 in d_out): z_q_st [N*D], indices-as-float [N], loss [1].
//
// R9 = R8 + ONE mechanism fix: slice id through readfirstlane.
// R8 post-mortem: slice = threadIdx.x>>6 made the embT pointer formally
// divergent (SGPR_Count 112->64, s_load gone, per-lane VMEM broadcast,
// VALUBusy 15.5%). readfirstlane pins the (genuinely wave-uniform) slice in
// an SGPR -> uniform e pointers -> s_load_dwordx16 + SGPR-operand v_fmac.
// Structure kept from R8: 64 tokens/block staged once into padded LDS
// (FETCH 34MB, ideal), codebook split across 4 waves, acc[32] panels
// (<64 VGPR, the proven allocator cap), 18.9KB LDS -> 8 blocks/CU ->
// 8 waves/SIMD for latency hiding.

static constexpr int N_TOK   = 262144;
static constexpr int K       = 512;
static constexpr int D       = 64;
static constexpr int BLK     = 256;          // 4 waves
static constexpr int TPB     = 64;           // tokens per block
static constexpr int NBLK    = N_TOK / TPB;  // 4096
static constexpr int NSLICE  = 4;            // one slice per wave
static constexpr int SLICE   = K / NSLICE;   // 128 codes
static constexpr int PANEL   = 32;
static constexpr int PPS     = SLICE / PANEL;  // 4 sub-panels
static constexpr int ZSTRIDE = D + 1;        // 65 -> ds_read_b32 2-way = free

// ---- prep 0: esq[k] = ||e_k||^2 --------------------------------------------
__global__ void esq_kernel(const float* __restrict__ emb, float* __restrict__ esq) {
  int k = threadIdx.x;
  if (k < K) {
    const float4* row = reinterpret_cast<const float4*>(emb + (size_t)k * D);
    float s = 0.f;
#pragma unroll
    for (int i = 0; i < D / 4; ++i) {
      float4 v = row[i];
      s = fmaf(v.x, v.x, s);
      s = fmaf(v.y, v.y, s);
      s = fmaf(v.z, v.z, s);
      s = fmaf(v.w, v.w, s);
    }
    esq[k] = s;
  }
}

// ---- prep 1: embT[d][c] = emb[c][d] ----------------------------------------
__global__ __launch_bounds__(512) void embT_kernel(
    const float* __restrict__ emb, float* __restrict__ embT) {
  int idx = blockIdx.x * 512 + threadIdx.x;  // 64 blocks x 512
  int d = idx >> 9;
  int c = idx & 511;
  embT[idx] = emb[c * D + d];
}

// ---- main ------------------------------------------------------------------
__global__ __launch_bounds__(BLK) void vq_main(
    const float* __restrict__ z_e, const float* __restrict__ emb,
    const float* __restrict__ embT, const float* __restrict__ esq,
    float* __restrict__ out_zq, float* __restrict__ out_idx,
    float* __restrict__ block_loss) {
  __shared__ float zs[TPB * ZSTRIDE];     // 64*65*4 = 16.64 KiB
  __shared__ float fb[NSLICE][TPB];       // per-slice best distance
  __shared__ int   fi[NSLICE][TPB];       // per-slice best index

  const int t   = threadIdx.x;
  const int tok = t & 63;                 // lane = token
  // Wave-uniform by construction; readfirstlane makes it SGPR-provable so
  // every embT/esq pointer below scalarizes to s_load (the R8 failure).
  const int slice = __builtin_amdgcn_readfirstlane(t >> 6);
  const int gtok0 = blockIdx.x * TPB;

  // Stage 64 z rows once (coalesced float4 reads, scalar scatter into pad).
  {
    const float4* Z4 = reinterpret_cast<const float4*>(z_e + (size_t)gtok0 * D);
#pragma unroll
    for (int i = 0; i < (TPB * D / 4) / BLK; ++i) {  // 4 iters
      int i4 = t + i * BLK;               // 0..1023
      float4 v = Z4[i4];
      int tk = i4 >> 4;                   // 16 float4 per token
      int d4 = (i4 & 15) << 2;
      float* p = &zs[tk * ZSTRIDE + d4];
      p[0] = v.x; p[1] = v.y; p[2] = v.z; p[3] = v.w;
    }
  }
  __syncthreads();

  const float* zrow  = &zs[tok * ZSTRIDE];
  const int    cbase = slice * SLICE;

  float best = 3.402823466e38f;
  int   bidx = 0;

  for (int p = 0; p < PPS; ++p) {
    const float* Ep = embT + cbase + p * PANEL;  // SGPR-uniform; +d*K per row
    const float* es = esq + cbase + p * PANEL;   // SGPR-uniform
    float acc[PANEL];
#pragma unroll
    for (int c = 0; c < PANEL; ++c) acc[c] = 0.f;

    // d ascending, single acc chain per code == R5-R8 order (absmax 0).
#pragma unroll 8
    for (int d = 0; d < D; ++d) {
      float zd = zrow[d];                 // ds_read_b32, bank (tok+d)%32
      const float* e = Ep + (size_t)d * K;
#pragma unroll
      for (int c = 0; c < PANEL; ++c) acc[c] = fmaf(zd, e[c], acc[c]);
    }

#pragma unroll
    for (int c = 0; c < PANEL; ++c) {
      float s = fmaf(-2.f, acc[c], es[c]);
      // Ascending c within ascending panels + strict < -> first-min ties.
      if (s < best) { best = s; bidx = cbase + p * PANEL + c; }
    }
  }

  fb[slice][tok] = best;
  fi[slice][tok] = bidx;
  __syncthreads();

  // Wave 0: combine 4 slice candidates per token (ascending slice order),
  // then gather + z_q_st write + loss for its lane's token.
  if (slice == 0) {
    float b  = fb[0][tok];
    int   bi = fi[0][tok];
#pragma unroll
    for (int s2 = 1; s2 < NSLICE; ++s2) {
      float v  = fb[s2][tok];
      int   vi = fi[s2][tok];
      if (v < b) { b = v; bi = vi; }  // strict <: lower slice wins ties
    }

    const int n = gtok0 + tok;
    float lsum = 0.f;
    {
      const float4* er = reinterpret_cast<const float4*>(emb + (size_t)bi * D);
      float4* orow = reinterpret_cast<float4*>(out_zq + (size_t)n * D);
#pragma unroll
      for (int i = 0; i < D / 4; ++i) {
        float4 q = er[i];
        float z0 = zrow[4 * i + 0], z1 = zrow[4 * i + 1];
        float z2 = zrow[4 * i + 2], z3 = zrow[4 * i + 3];
        float dx = q.x - z0, dy = q.y - z1, dz = q.z - z2, dw = q.w - z3;
        float4 st;
        st.x = z0 + dx; st.y = z1 + dy; st.z = z2 + dz; st.w = z3 + dw;
        orow[i] = st;
        lsum = fmaf(dx, dx, lsum);
        lsum = fmaf(dy, dy, lsum);
        lsum = fmaf(dz, dz, lsum);
        lsum = fmaf(dw, dw, lsum);
      }
    }
    out_idx[n] = (float)bi;

    // Deterministic 64-lane butterfly sum (same sequence every launch).
    float s = lsum;
#pragma unroll
    for (int off = 32; off > 0; off >>= 1) s += __shfl_xor(s, off, 64);
    if (tok == 0) block_loss[blockIdx.x] = s;
  }
}

// ---- finalize loss (deterministic tree) ------------------------------------
__global__ __launch_bounds__(256) void loss_finalize(
    const float* __restrict__ bl, float* __restrict__ out_loss) {
  __shared__ float sm[256];
  float s = 0.f;
  for (int i = threadIdx.x; i < NBLK; i += 256) s += bl[i];
  sm[threadIdx.x] = s;
  __syncthreads();
#pragma unroll
  for (int off = 128; off > 0; off >>= 1) {
    if (threadIdx.x < off) sm[threadIdx.x] += sm[threadIdx.x + off];
    __syncthreads();
  }
  if (threadIdx.x == 0) out_loss[0] = sm[0] * (1.0f / 16777216.0f);  // /(N*D)
}

extern "C" void kernel_launch(void* const* d_in, const int* in_sizes, int n_in,
                              void* d_out, int out_size, void* d_ws, size_t ws_size,
                              hipStream_t stream) {
  const float* z_e = (const float*)d_in[0];
  const float* emb = (const float*)d_in[1];

  float* out      = (float*)d_out;
  float* out_zq   = out;                          // N*D
  float* out_idx  = out + (size_t)N_TOK * D;      // N
  float* out_loss = out_idx + N_TOK;              // 1

  float* esq  = (float*)d_ws;            // K floats
  float* bl   = esq + K;                 // NBLK floats (4096)
  float* embT = bl + NBLK;               // K*D floats (128 KiB)

  esq_kernel<<<1, K, 0, stream>>>(emb, esq);
  embT_kernel<<<(K * D) / 512, 512, 0, stream>>>(emb, embT);
  vq_main<<<NBLK, BLK, 0, stream>>>(z_e, emb, embT, esq, out_zq, out_idx, bl);
  loss_finalize<<<1, 256, 0, stream>>>(bl, out_loss);
}

// Round 10
// 213.478 us; speedup vs baseline: 4.4267x; 1.0050x over previous
//
#include <hip/hip_runtime.h>

// VQ codebook: z_e (262144, 64) f32, embeddings (512, 64) f32.
// Outputs (flat f32 in d_out): z_q_st [N*D], indices-as-float [N], loss [1].
//
// R10 = R9 + (1) z via ds_read_b128 (ZSTRIDE 68, 16B-aligned): 16 lgkm wait
// events/panel instead of 64 against the s_load e-stream (lgkm mixing was a
// stall source), and (2) parallel epilogue: 4 threads/token across all 4
// waves (R9 ran gather+write+loss on wave 0 only).
// Kept from R9 (each proven by a counter flip): slice id via readfirstlane
// (s_load operands, R8->R9 SGPR 64->112), acc[32] panels < 64-VGPR allocator
// cap (R1-R7), z staged once to LDS (R6's 850MB re-read wall), 19.5KB LDS ->
// 8 blocks/CU latency hiding (R5's 2-block stall).

static constexpr int N_TOK   = 262144;
static constexpr int K       = 512;
static constexpr int D       = 64;
static constexpr int BLK     = 256;          // 4 waves
static constexpr int TPB     = 64;           // tokens per block
static constexpr int NBLK    = N_TOK / TPB;  // 4096
static constexpr int NSLICE  = 4;            // one code slice per wave
static constexpr int SLICE   = K / NSLICE;   // 128 codes
static constexpr int PANEL   = 32;
static constexpr int PPS     = SLICE / PANEL;  // 4 sub-panels
static constexpr int ZSTRIDE = 68;           // 68*4B = 272B: 16B-aligned rows

// ---- prep 0: esq[k] = ||e_k||^2 --------------------------------------------
__global__ void esq_kernel(const float* __restrict__ emb, float* __restrict__ esq) {
  int k = threadIdx.x;
  if (k < K) {
    const float4* row = reinterpret_cast<const float4*>(emb + (size_t)k * D);
    float s = 0.f;
#pragma unroll
    for (int i = 0; i < D / 4; ++i) {
      float4 v = row[i];
      s = fmaf(v.x, v.x, s);
      s = fmaf(v.y, v.y, s);
      s = fmaf(v.z, v.z, s);
      s = fmaf(v.w, v.w, s);
    }
    esq[k] = s;
  }
}

// ---- prep 1: embT[d][c] = emb[c][d] ----------------------------------------
__global__ __launch_bounds__(512) void embT_kernel(
    const float* __restrict__ emb, float* __restrict__ embT) {
  int idx = blockIdx.x * 512 + threadIdx.x;  // 64 blocks x 512
  int d = idx >> 9;
  int c = idx & 511;
  embT[idx] = emb[c * D + d];
}

// ---- main ------------------------------------------------------------------
__global__ __launch_bounds__(BLK) void vq_main(
    const float* __restrict__ z_e, const float* __restrict__ emb,
    const float* __restrict__ embT, const float* __restrict__ esq,
    float* __restrict__ out_zq, float* __restrict__ out_idx,
    float* __restrict__ block_loss) {
  __shared__ float zs[TPB * ZSTRIDE];     // 64*68*4 = 17.0 KiB
  __shared__ float fb[NSLICE][TPB];       // per-slice best distance
  __shared__ int   fi[NSLICE][TPB];       // per-slice best index
  __shared__ float ws[NSLICE];            // per-wave loss partials

  const int t   = threadIdx.x;
  const int tok = t & 63;                 // lane = token
  // Wave-uniform; readfirstlane pins it in an SGPR so embT/esq pointers
  // scalarize to s_load (the R8->R9 lesson).
  const int slice = __builtin_amdgcn_readfirstlane(t >> 6);
  const int gtok0 = blockIdx.x * TPB;

  // Stage 64 z rows once (coalesced float4 reads, 16B-aligned LDS writes).
  {
    const float4* Z4 = reinterpret_cast<const float4*>(z_e + (size_t)gtok0 * D);
#pragma unroll
    for (int i = 0; i < (TPB * D / 4) / BLK; ++i) {  // 4 iters
      int i4 = t + i * BLK;               // 0..1023
      float4 v = Z4[i4];
      int tk = i4 >> 4;                   // 16 float4 per token
      int d4 = (i4 & 15) << 2;
      *reinterpret_cast<float4*>(&zs[tk * ZSTRIDE + d4]) = v;
    }
  }
  __syncthreads();

  const float4* zrow4 =
      reinterpret_cast<const float4*>(&zs[tok * ZSTRIDE]);
  const int cbase = slice * SLICE;

  float best = 3.402823466e38f;
  int   bidx = 0;

  for (int p = 0; p < PPS; ++p) {
    const float* Ep = embT + cbase + p * PANEL;  // SGPR-uniform; +d*K per row
    const float* es = esq + cbase + p * PANEL;   // SGPR-uniform
    float acc[PANEL];
#pragma unroll
    for (int c = 0; c < PANEL; ++c) acc[c] = 0.f;

    // d ascending (4i+{0,1,2,3}) -> accumulation order identical to R5-R9.
    // One ds_read_b128 feeds 128 FMAs (vs 4x ds_read_b32 in R9).
#pragma unroll 4
    for (int i = 0; i < D / 4; ++i) {
      float4 zq = zrow4[i];               // ds_read_b128
      const float* e = Ep + (size_t)(4 * i) * K;
#pragma unroll
      for (int c = 0; c < PANEL; ++c) acc[c] = fmaf(zq.x, e[c], acc[c]);
      e += K;
#pragma unroll
      for (int c = 0; c < PANEL; ++c) acc[c] = fmaf(zq.y, e[c], acc[c]);
      e += K;
#pragma unroll
      for (int c = 0; c < PANEL; ++c) acc[c] = fmaf(zq.z, e[c], acc[c]);
      e += K;
#pragma unroll
      for (int c = 0; c < PANEL; ++c) acc[c] = fmaf(zq.w, e[c], acc[c]);
    }

#pragma unroll
    for (int c = 0; c < PANEL; ++c) {
      float s = fmaf(-2.f, acc[c], es[c]);
      // Ascending c within ascending panels + strict < -> first-min ties.
      if (s < best) { best = s; bidx = cbase + p * PANEL + c; }
    }
  }

  fb[slice][tok] = best;
  fi[slice][tok] = bidx;
  __syncthreads();

  // Parallel epilogue: 4 threads per token (q = chunk quarter), all waves.
  {
    const int tokE = t >> 2;              // 0..63
    const int q    = t & 3;

    // All 4 threads of a token compute the same combine (ascending slice
    // order, strict < -> lower slice wins ties == jnp first-min).
    float b  = fb[0][tokE];
    int   bi = fi[0][tokE];
#pragma unroll
    for (int s2 = 1; s2 < NSLICE; ++s2) {
      float v = fb[s2][tokE];
      if (v < b) { b = v; bi = fi[s2][tokE]; }
    }

    const int n = gtok0 + tokE;
    const float4* er = reinterpret_cast<const float4*>(emb + (size_t)bi * D);
    const float4* zr = reinterpret_cast<const float4*>(&zs[tokE * ZSTRIDE]);
    float4* orow = reinterpret_cast<float4*>(out_zq + (size_t)n * D);

    float lsum = 0.f;
#pragma unroll
    for (int j = 0; j < 4; ++j) {
      int i = 4 * q + j;
      float4 Q = er[i];
      float4 Z = zr[i];
      float dx = Q.x - Z.x, dy = Q.y - Z.y, dz = Q.z - Z.z, dw = Q.w - Z.w;
      float4 st;
      st.x = Z.x + dx; st.y = Z.y + dy; st.z = Z.z + dz; st.w = Z.w + dw;
      orow[i] = st;
      lsum = fmaf(dx, dx, lsum);
      lsum = fmaf(dy, dy, lsum);
      lsum = fmaf(dz, dz, lsum);
      lsum = fmaf(dw, dw, lsum);
    }
    if (q == 0) out_idx[n] = (float)bi;

    // Deterministic loss: 64-lane butterfly per wave, fixed-order combine.
    float s = lsum;
#pragma unroll
    for (int off = 32; off > 0; off >>= 1) s += __shfl_xor(s, off, 64);
    if ((t & 63) == 0) ws[t >> 6] = s;
  }
  __syncthreads();
  if (t == 0)
    block_loss[blockIdx.x] = ((ws[0] + ws[1]) + ws[2]) + ws[3];
}

// ---- finalize loss (deterministic tree) ------------------------------------
__global__ __launch_bounds__(256) void loss_finalize(
    const float* __restrict__ bl, float* __restrict__ out_loss) {
  __shared__ float sm[256];
  float s = 0.f;
  for (int i = threadIdx.x; i < NBLK; i += 256) s += bl[i];
  sm[threadIdx.x] = s;
  __syncthreads();
#pragma unroll
  for (int off = 128; off > 0; off >>= 1) {
    if (threadIdx.x < off) sm[threadIdx.x] += sm[threadIdx.x + off];
    __syncthreads();
  }
  if (threadIdx.x == 0) out_loss[0] = sm[0] * (1.0f / 16777216.0f);  // /(N*D)
}

extern "C" void kernel_launch(void* const* d_in, const int* in_sizes, int n_in,
                              void* d_out, int out_size, void* d_ws, size_t ws_size,
                              hipStream_t stream) {
  const float* z_e = (const float*)d_in[0];
  const float* emb = (const float*)d_in[1];

  float* out      = (float*)d_out;
  float* out_zq   = out;                          // N*D
  float* out_idx  = out + (size_t)N_TOK * D;      // N
  float* out_loss = out_idx + N_TOK;              // 1

  float* esq  = (float*)d_ws;            // K floats
  float* bl   = esq + K;                 // NBLK floats (4096)
  float* embT = bl + NBLK;               // K*D floats (128 KiB)

  esq_kernel<<<1, K, 0, stream>>>(emb, esq);
  embT_kernel<<<(K * D) / 512, 512, 0, stream>>>(emb, embT);
  vq_main<<<NBLK, BLK, 0, stream>>>(z_e, emb, embT, esq, out_zq, out_idx, bl);
  loss_finalize<<<1, 256, 0, stream>>>(bl, out_loss);
}

// Round 11
// 190.056 us; speedup vs baseline: 4.9722x; 1.1232x over previous
//
#include <hip/hip_runtime.h>

// VQ codebook via MFMA: z_e (262144,64) f32, embeddings (512,64) f32.
// Outputs (flat f32): z_q_st [N*D], indices-as-float [N], loss [1].
//
// R11: distances on the MATRIX pipe. d~ = esq + Z*(-2E)^T computed with a
// bf16 two-term split (3 products, lo*lo dropped; |err| <= ~3e-3) using
// mfma_f32_16x16x32_bf16 (C/D layout col=lane&15,row=(lane>>4)*4+reg,
// HW-verified). Exactness guard: per token track best AND second-best of d~;
// if gap < 0.02 (>6x error bound) flag -> exact f32 rescan (R10-proven path).
// R10 lesson: f32-VALU floor is 109us; structure was at its ceiling (222us).
// Carried: readfirstlane-free design (all operands per-lane vector or LDS),
// <64 VGPR live set, z staged once (R6), E reused via LDS across waves.

typedef short  bf16x8 __attribute__((ext_vector_type(8)));
typedef float  f32x4  __attribute__((ext_vector_type(4)));

static constexpr int N_TOK = 262144;
static constexpr int K     = 512;
static constexpr int D     = 64;
static constexpr float THRESH = 0.02f;
static constexpr int NBLK_OUT = N_TOK / 64;   // 4096 (kernel C blocks)

// ws layout (bytes, all 16B-aligned where needed)
static constexpr size_t WS_ESQ   = 0;         //  512 f32   (2048 B)
static constexpr size_t WS_BL    = 2048;      // 4096 f32   (16384 B)
static constexpr size_t WS_CNT   = 18432;     // 1 uint
static constexpr size_t WS_EFRAG = 18448;     // 65536 u16  (131072 B)
static constexpr size_t WS_BIDX  = 149520;    // 262144 int (1 MB)
static constexpr size_t WS_LIST  = 1198096;   // 262144 uint(1 MB)

// ---- prep 0: esq[k] = ||e_k||^2 (f32, unscaled) ----------------------------
__global__ void esq_kernel(const float* __restrict__ emb, float* __restrict__ esq) {
  int k = threadIdx.x;
  if (k < K) {
    const float4* row = reinterpret_cast<const float4*>(emb + (size_t)k * D);
    float s = 0.f;
#pragma unroll
    for (int i = 0; i < D / 4; ++i) {
      float4 v = row[i];
      s = fmaf(v.x, v.x, s); s = fmaf(v.y, v.y, s);
      s = fmaf(v.z, v.z, s); s = fmaf(v.w, v.w, s);
    }
    esq[k] = s;
  }
}

// ---- prep 1: E' = -2E -> bf16 hi/lo in A-fragment order --------------------
// A-frag (16x16x32): row = lane&15, k = (lane>>4)*8 + i.
// slot(tile,c,part,lane) = tile*256 + c*128 + part*64 + lane; u16 = slot*8+i.
__global__ __launch_bounds__(512) void efrag_kernel(
    const float* __restrict__ emb, unsigned short* __restrict__ ef) {
  int idx  = blockIdx.x * 512 + threadIdx.x;   // 32768 = 512 codes * 64 d
  int code = idx >> 6, d = idx & 63;
  float s  = -2.0f * emb[code * 64 + d];       // exact scale
  unsigned u  = __float_as_uint(s);
  unsigned hi = (u + 0x7FFFu + ((u >> 16) & 1u)) >> 16;       // RNE bf16
  float lof   = s - __uint_as_float(hi << 16);                // exact residual
  unsigned v2 = __float_as_uint(lof);
  unsigned lo = (v2 + 0x7FFFu + ((v2 >> 16) & 1u)) >> 16;     // RNE bf16
  int tile = code >> 4, row = code & 15;
  int c = (d >> 5) & 1, g = (d >> 3) & 3, i = d & 7;
  int lane = row + (g << 4);
  size_t base = ((size_t)tile * 256 + (size_t)c * 128) * 8;
  ef[base + (size_t)(0 * 64 + lane) * 8 + i] = (unsigned short)hi;
  ef[base + (size_t)(1 * 64 + lane) * 8 + i] = (unsigned short)lo;
}

// ---- kernel A: MFMA distances + best/second/argmin + flag ------------------
__global__ __launch_bounds__(256) void vq_mfma(
    const float* __restrict__ z_e, const unsigned short* __restrict__ efrag,
    const float* __restrict__ esq_g, int* __restrict__ bidx,
    unsigned* __restrict__ list, unsigned* __restrict__ cnt) {
  __shared__ float zs[64 * 68];                  // 17408 B, pad 68 f32/row
  __shared__ float esql[K];                      // 2048 B
  __shared__ __align__(16) short lds_eb[2][2048]; // 2 x 4KB E-tile dbuf

  const int t = threadIdx.x;
  const int gtok0 = blockIdx.x * 64;

  // Stage 64 z rows (coalesced float4) + esq.
  {
    const float4* Z4 = reinterpret_cast<const float4*>(z_e + (size_t)gtok0 * D);
#pragma unroll
    for (int i = 0; i < 4; ++i) {
      int i4 = t + i * 256;
      float4 v = Z4[i4];
      int tk = i4 >> 4, d4 = (i4 & 15) << 2;
      *reinterpret_cast<float4*>(&zs[tk * 68 + d4]) = v;
    }
    esql[t] = esq_g[t];
    esql[t + 256] = esq_g[t + 256];
  }
  __syncthreads();

  const int l = t & 63, w = t >> 6;
  const int g = l >> 4, g4 = g << 2;
  const int lr = (w << 4) + (l & 15);            // this lane's token row in zs

  // B-frags: z[tok][32c + g*8 + i] -> bf16 hi/lo (RNE split, same as efrag).
  bf16x8 zh0, zl0, zh1, zl1;
  {
    float a[8], b[8];
    const float* zp0 = &zs[lr * 68 + g * 8];
    const float* zp1 = zp0 + 32;
    float4 q;
    q = *reinterpret_cast<const float4*>(zp0);     a[0]=q.x;a[1]=q.y;a[2]=q.z;a[3]=q.w;
    q = *reinterpret_cast<const float4*>(zp0 + 4); a[4]=q.x;a[5]=q.y;a[6]=q.z;a[7]=q.w;
    q = *reinterpret_cast<const float4*>(zp1);     b[0]=q.x;b[1]=q.y;b[2]=q.z;b[3]=q.w;
    q = *reinterpret_cast<const float4*>(zp1 + 4); b[4]=q.x;b[5]=q.y;b[6]=q.z;b[7]=q.w;
#pragma unroll
    for (int i = 0; i < 8; ++i) {
      unsigned u  = __float_as_uint(a[i]);
      unsigned hi = (u + 0x7FFFu + ((u >> 16) & 1u)) >> 16;
      float lof   = a[i] - __uint_as_float(hi << 16);
      unsigned v2 = __float_as_uint(lof);
      unsigned lo = (v2 + 0x7FFFu + ((v2 >> 16) & 1u)) >> 16;
      zh0[i] = (short)hi; zl0[i] = (short)lo;
      u  = __float_as_uint(b[i]);
      hi = (u + 0x7FFFu + ((u >> 16) & 1u)) >> 16;
      lof = b[i] - __uint_as_float(hi << 16);
      v2 = __float_as_uint(lof);
      lo = (v2 + 0x7FFFu + ((v2 >> 16) & 1u)) >> 16;
      zh1[i] = (short)hi; zl1[i] = (short)lo;
    }
  }

  const bf16x8* EF = reinterpret_cast<const bf16x8*>(efrag);
  // Prime E-tile 0 into buffer 0.
  {
    bf16x8 pre = EF[t];
    *(reinterpret_cast<bf16x8*>(&lds_eb[0][0]) + t) = pre;
  }
  __syncthreads();

  float best = 3.402823466e38f, second = 3.402823466e38f;
  int bidxv = 0;
  int buf = 0;

  for (int tile = 0; tile < 32; ++tile) {
    bf16x8 nxt;
    if (tile < 31) nxt = EF[(size_t)(tile + 1) * 256 + t];  // issue early

    f32x4 C = *reinterpret_cast<const f32x4*>(&esql[tile * 16 + g4]); // C=esq
    const bf16x8* eb = reinterpret_cast<const bf16x8*>(&lds_eb[buf][0]);
    bf16x8 ah0 = eb[l], al0 = eb[64 + l], ah1 = eb[128 + l], al1 = eb[192 + l];

    // d~ = esq + E'h*Zh + E'h*Zl + E'l*Zh   (per 32-k chunk)
    C = __builtin_amdgcn_mfma_f32_16x16x32_bf16(ah0, zh0, C, 0, 0, 0);
    C = __builtin_amdgcn_mfma_f32_16x16x32_bf16(ah0, zl0, C, 0, 0, 0);
    C = __builtin_amdgcn_mfma_f32_16x16x32_bf16(al0, zh0, C, 0, 0, 0);
    C = __builtin_amdgcn_mfma_f32_16x16x32_bf16(ah1, zh1, C, 0, 0, 0);
    C = __builtin_amdgcn_mfma_f32_16x16x32_bf16(ah1, zl1, C, 0, 0, 0);
    C = __builtin_amdgcn_mfma_f32_16x16x32_bf16(al1, zh1, C, 0, 0, 0);

    const int base = tile * 16 + g4;  // codes ascend over (tile, r) per lane
#pragma unroll
    for (int r = 0; r < 4; ++r) {
      float v = C[r];
      bool lt = v < best;
      float mn = fminf(second, v);
      second = lt ? best : mn;
      bidxv  = lt ? (base + r) : bidxv;
      best   = lt ? v : best;
    }

    if (tile < 31)
      *(reinterpret_cast<bf16x8*>(&lds_eb[buf ^ 1][0]) + t) = nxt;
    __syncthreads();
    buf ^= 1;
  }

  // Reduce token's 4 lanes {l, l+16, l+32, l+48}; ties -> smaller code.
#pragma unroll
  for (int mask = 16; mask <= 32; mask <<= 1) {
    float ob = __shfl_xor(best, mask);
    int   oi = __shfl_xor(bidxv, mask);
    float os = __shfl_xor(second, mask);
    float hi2 = fmaxf(best, ob);
    second = fminf(second, fminf(os, hi2));
    bool take = (ob < best) || (ob == best && oi < bidxv);
    best  = take ? ob : best;
    bidxv = take ? oi : bidxv;
  }

  if (l < 16) {
    int n = gtok0 + (w << 4) + l;
    bool flag = (second - best) < THRESH;      // gap guard (>=6x err bound)
    bidx[n] = bidxv | (flag ? 0x40000000 : 0);
    if (flag) {
      unsigned pos = atomicAdd(cnt, 1u);
      list[pos] = (unsigned)n;                 // CAP = N, cannot overflow
    }
  }
}

// ---- kernel B: exact f32 rescan of flagged tokens (wave per token) ---------
__global__ __launch_bounds__(256) void vq_fix(
    const float* __restrict__ z_e, const float* __restrict__ emb,
    const float* __restrict__ esq_g, int* __restrict__ bidx,
    const unsigned* __restrict__ list, const unsigned* __restrict__ cnt) {
  const int l = threadIdx.x & 63;
  const int wid = blockIdx.x * 4 + (threadIdx.x >> 6);
  const unsigned n_flag = *cnt;
  for (unsigned j = wid; j < n_flag; j += 256 * 4) {
    const int n = (int)list[j];
    const float4* zr = reinterpret_cast<const float4*>(z_e + (size_t)n * D);
    float acc[8];
#pragma unroll
    for (int m = 0; m < 8; ++m) acc[m] = 0.f;
    // d ascending fmaf chain per code == R10's proven exact order.
#pragma unroll 4
    for (int i = 0; i < 16; ++i) {
      float4 z4 = zr[i];                       // uniform addr, L1-hot
#pragma unroll
      for (int m = 0; m < 8; ++m) {
        const float4 e4 = *reinterpret_cast<const float4*>(
            emb + (size_t)(l + 64 * m) * D + 4 * i);
        acc[m] = fmaf(z4.x, e4.x, acc[m]);
        acc[m] = fmaf(z4.y, e4.y, acc[m]);
        acc[m] = fmaf(z4.z, e4.z, acc[m]);
        acc[m] = fmaf(z4.w, e4.w, acc[m]);
      }
    }
    float best = 3.402823466e38f; int bid = 0;
#pragma unroll
    for (int m = 0; m < 8; ++m) {
      float s = fmaf(-2.f, acc[m], esq_g[l + 64 * m]);
      if (s < best) { best = s; bid = l + 64 * m; }  // ascending within lane
    }
#pragma unroll
    for (int mask = 1; mask <= 32; mask <<= 1) {     // lexicographic min
      float ob = __shfl_xor(best, mask);
      int   oi = __shfl_xor(bid, mask);
      bool take = (ob < best) || (ob == best && oi < bid);
      best = take ? ob : best;
      bid  = take ? oi : bid;
    }
    if (l == 0) bidx[n] = bid;                 // clean (no flag bit)
  }
}

// ---- kernel C: gather + z_q_st + idx float + deterministic loss ------------
__global__ __launch_bounds__(256) void vq_out(
    const float* __restrict__ z_e, const float* __restrict__ emb,
    const int* __restrict__ bidx, float* __restrict__ out_zq,
    float* __restrict__ out_idx, float* __restrict__ block_loss) {
  __shared__ float wsm[4];
  const int t = threadIdx.x;
  const int tokE = t >> 2, q = t & 3;
  const int n = blockIdx.x * 64 + tokE;
  const int bi = bidx[n] & 511;
  const float4* er = reinterpret_cast<const float4*>(emb + (size_t)bi * D);
  const float4* zr = reinterpret_cast<const float4*>(z_e + (size_t)n * D);
  float4* orow = reinterpret_cast<float4*>(out_zq + (size_t)n * D);
  float lsum = 0.f;
#pragma unroll
  for (int j = 0; j < 4; ++j) {
    int i = 4 * q + j;
    float4 Q = er[i], Z = zr[i];
    float dx = Q.x - Z.x, dy = Q.y - Z.y, dz = Q.z - Z.z, dw = Q.w - Z.w;
    float4 st;
    st.x = Z.x + dx; st.y = Z.y + dy; st.z = Z.z + dz; st.w = Z.w + dw;
    orow[i] = st;
    lsum = fmaf(dx, dx, lsum); lsum = fmaf(dy, dy, lsum);
    lsum = fmaf(dz, dz, lsum); lsum = fmaf(dw, dw, lsum);
  }
  if (q == 0) out_idx[n] = (float)bi;
  float s = lsum;
#pragma unroll
  for (int off = 32; off > 0; off >>= 1) s += __shfl_xor(s, off, 64);
  if ((t & 63) == 0) wsm[t >> 6] = s;
  __syncthreads();
  if (t == 0) block_loss[blockIdx.x] = ((wsm[0] + wsm[1]) + wsm[2]) + wsm[3];
}

// ---- finalize loss (deterministic tree) ------------------------------------
__global__ __launch_bounds__(256) void loss_finalize(
    const float* __restrict__ bl, float* __restrict__ out_loss) {
  __shared__ float sm[256];
  float s = 0.f;
  for (int i = threadIdx.x; i < NBLK_OUT; i += 256) s += bl[i];
  sm[threadIdx.x] = s;
  __syncthreads();
#pragma unroll
  for (int off = 128; off > 0; off >>= 1) {
    if (threadIdx.x < off) sm[threadIdx.x] += sm[threadIdx.x + off];
    __syncthreads();
  }
  if (threadIdx.x == 0) out_loss[0] = sm[0] * (1.0f / 16777216.0f);  // /(N*D)
}

extern "C" void kernel_launch(void* const* d_in, const int* in_sizes, int n_in,
                              void* d_out, int out_size, void* d_ws, size_t ws_size,
                              hipStream_t stream) {
  const float* z_e = (const float*)d_in[0];
  const float* emb = (const float*)d_in[1];

  float* out      = (float*)d_out;
  float* out_zq   = out;                          // N*D
  float* out_idx  = out + (size_t)N_TOK * D;      // N
  float* out_loss = out_idx + N_TOK;              // 1

  char* wsb = (char*)d_ws;
  float*          esqp = (float*)(wsb + WS_ESQ);
  float*          bl   = (float*)(wsb + WS_BL);
  unsigned*       cntp = (unsigned*)(wsb + WS_CNT);
  unsigned short* ef   = (unsigned short*)(wsb + WS_EFRAG);
  int*            bidx = (int*)(wsb + WS_BIDX);
  unsigned*       list = (unsigned*)(wsb + WS_LIST);

  hipMemsetAsync(cntp, 0, 4, stream);
  esq_kernel<<<1, 512, 0, stream>>>(emb, esqp);
  efrag_kernel<<<64, 512, 0, stream>>>(emb, ef);
  vq_mfma<<<N_TOK / 64, 256, 0, stream>>>(z_e, ef, esqp, bidx, list, cntp);
  vq_fix<<<256, 256, 0, stream>>>(z_e, emb, esqp, bidx, list, cntp);
  vq_out<<<NBLK_OUT, 256, 0, stream>>>(z_e, emb, bidx, out_zq, out_idx, bl);
  loss_finalize<<<1, 256, 0, stream>>>(bl, out_loss);
}